// Round 10
// baseline (199.907 us; speedup 1.0000x reference)
//
#include <hip/hip_runtime.h>

// Problem constants (fixed by setup_inputs):
//   a_arc, s_arc : [64, 1024, 1024] f32
//   adds, pos    : [64, 1024] int32 in [0, 50)
constexpr int NPOS  = 50;
constexpr int NBINS = NPOS * NPOS;   // 2500
constexpr int SL    = 1024;
constexpr int BZ    = 64;
constexpr float ALPHA = 0.3f;

using f32x4  = __attribute__((ext_vector_type(4))) float;
using bf16x8 = __attribute__((ext_vector_type(8))) short;

// ---------------- hist (MFMA) config — structure as R8 ----------------
constexpr int H_THREADS = 256;                    // 4 waves, 16 rows each
constexpr int H_ROWS    = 64;                     // rows per block
constexpr int KSPLIT    = 2;                      // j-halves (K=512/block)
constexpr int KSTEPS    = (SL / KSPLIT) / 32;     // 16 K-steps of 32
constexpr int H_BLOCKS  = BZ * (SL / H_ROWS) * KSPLIT;  // 2048
constexpr int PSTRIDE   = 2560;                   // partial-slice stride (floats)

// ---------------- E-fragment precompute config ----------------
// Efrag[((bkh*16 + ks)*64 + lane)*4 + qt] : uint4 (16 B) == bf16x8 B-fragment.
// 128 bkh x 16 ks x 64 lanes x 4 qt x 16 B = 8 MB, built once per launch.
constexpr int E_THREADS = 256;
constexpr int E_TOTAL   = BZ * KSPLIT * KSTEPS * 64;    // 131072 fragments sets
constexpr int E_BLOCKS  = E_TOTAL / E_THREADS;          // 512

// ---------------- reduce config ----------------
constexpr int R_THREADS = 256;                    // 4 waves x 64 bins
constexpr int R_BINGRP  = 40;                     // ceil(2500/64)
constexpr int R_PGRP    = 16;                     // 2048/128 slices per group
constexpr int R_BLOCKS  = R_BINGRP * R_PGRP;      // 640

// ---------------- apply kernel config ----------------
constexpr int A_THREADS      = 256;
constexpr int ROWS_PER_BLOCK = 32;
constexpr int BLOCKS_PER_B   = SL / ROWS_PER_BLOCK;   // 32
constexpr int A_BLOCKS       = BZ * BLOCKS_PER_B;     // 2048

// ---------------------------------------------------------------------------
// Kernel 0: precompute one-hot E fragments (MFMA B-operand layout), hoisting
// the per-K-step cmp/cndmask/pack chain (~150 VALU instrs) out of the hist
// K-loop — R8 showed hist is VALU-issue-bound on exactly this construction.
// Mapping replicates R7/R8's verified in-loop build: fragment element e of
// lane (kg,l15), q-tile qt equals (adds[b][khalf*512 + ks*32 + kg*8 + e]
// == qt*16 + l15) ? bf16(1.0) : 0.
// ---------------------------------------------------------------------------
__global__ __launch_bounds__(E_THREADS) void efrag_kernel(
    const int* __restrict__ adds, uint4* __restrict__ efrag) {
  const int gid  = blockIdx.x * E_THREADS + threadIdx.x;  // (bkh*16+ks)*64+lane
  const int lane = gid & 63;
  const int ksg  = gid >> 6;
  const int ks   = ksg & 15;
  const int bkh  = ksg >> 4;
  const int b    = bkh >> 1, khalf = bkh & 1;
  const int kg   = lane >> 4, l15 = lane & 15;
  const int j    = khalf * (SL / KSPLIT) + ks * 32 + kg * 8;

  const int* __restrict__ ap = adds + (size_t)b * SL + j;
  int av[8];
  #pragma unroll
  for (int e = 0; e < 8; ++e) av[e] = ap[e];

  uint4* __restrict__ dst = efrag + (size_t)gid * 4;
  #pragma unroll
  for (int qt = 0; qt < 4; ++qt) {
    const int q = qt * 16 + l15;
    unsigned w[4];
    #pragma unroll
    for (int u = 0; u < 4; ++u) {
      const unsigned lo = (av[2 * u]     == q) ? 0x3F80u : 0u;
      const unsigned hi = (av[2 * u + 1] == q) ? 0x3F80u : 0u;
      w[u] = lo | (hi << 16);
    }
    dst[qt] = uint4{w[0], w[1], w[2], w[3]};
  }
}

// ---------------------------------------------------------------------------
// Kernel 1: score[p,q] partials via MFMA. Identical to R8 except the K-loop
// loads prebuilt E fragments (4 coalesced dwordx4, L2-resident, 16x block
// reuse) instead of rebuilding them with ~150 VALU instrs per K-step.
// ---------------------------------------------------------------------------
__global__ __launch_bounds__(H_THREADS) void hist_mfma(
    const float* __restrict__ a, const int* __restrict__ adds,
    const uint4* __restrict__ efrag, float* __restrict__ g_part) {
  __shared__ int   adds_s[SL];           // 4 KB
  __shared__ float T_lds[H_ROWS][66];    // 16.9 KB (pad 64->66: bank-safe)
  __shared__ float acc2[NPOS * 52];      // 10.4 KB partial S
  __shared__ int   orderR[H_ROWS];       // rows sorted by p
  __shared__ int   cntR[NPOS], offm[NPOS];

  const int tid   = threadIdx.x;
  const int b     = blockIdx.x >> 5;     // 32 blocks per batch
  const int rem   = blockIdx.x & 31;
  const int rblk  = rem >> 1;            // 0..15
  const int khalf = rem & 1;
  const int row0  = rblk * H_ROWS;
  const int j0b   = khalf * (SL / KSPLIT);
  const int bkh   = b * 2 + khalf;

  // --- stage adds row; zero counters/partials ---
  ((int4*)adds_s)[tid] = ((const int4*)(adds + (size_t)b * SL))[tid];
  for (int k = tid; k < NPOS * 52; k += H_THREADS) acc2[k] = 0.0f;
  if (tid < NPOS) cntR[tid] = 0;
  __syncthreads();

  // --- counting sort of the block's 64 rows by p = adds[row] ---
  if (tid < H_ROWS) atomicAdd(&cntR[adds_s[row0 + tid]], 1);
  __syncthreads();
  if (tid == 0) {
    int run = 0;
    for (int c = 0; c < NPOS; ++c) { offm[c] = run; run += cntR[c]; }
  }
  __syncthreads();
  if (tid < H_ROWS)
    orderR[atomicAdd(&offm[adds_s[row0 + tid]], 1)] = tid;
  // (orderR consumed only after the post-stage1 __syncthreads)

  // --- stage 1: T[r,q] = sum_j A[r,j] * (adds[j]==q), q in [0,64) ---
  const int wid = tid >> 6, lane = tid & 63;
  const int kg = lane >> 4, l15 = lane & 15;
  const float* __restrict__ Arow =
      a + ((size_t)b * SL + row0 + wid * 16 + l15) * SL + j0b + kg * 8;
  const uint4* __restrict__ Ebase = efrag + ((size_t)bkh * KSTEPS * 64 + lane) * 4;

  struct PF { float4 va, vb; uint4 e0, e1, e2, e3; };
  auto loadpf = [&](PF& buf, int ks) {
    const float* p_ = Arow + ks * 32;
    buf.va = ((const float4*)p_)[0];
    buf.vb = ((const float4*)p_)[1];
    const uint4* ep = Ebase + (size_t)ks * 64 * 4;
    buf.e0 = ep[0]; buf.e1 = ep[1]; buf.e2 = ep[2]; buf.e3 = ep[3];
  };

  f32x4 acc[4] = {};   // one per q-tile
  auto compute = [&](const PF& buf) {
    const float f[8] = {buf.va.x, buf.va.y, buf.va.z, buf.va.w,
                        buf.vb.x, buf.vb.y, buf.vb.z, buf.vb.w};
    bf16x8 ah, al;
    #pragma unroll
    for (int e = 0; e < 8; ++e) {
      const unsigned u = __builtin_bit_cast(unsigned, f[e]);
      ah[e] = (short)(u >> 16);
      const float hf = __builtin_bit_cast(float, u & 0xFFFF0000u);
      const float lo = f[e] - hf;                  // exact residue
      al[e] = (short)(__builtin_bit_cast(unsigned, lo) >> 16);
    }
    const bf16x8 b0 = __builtin_bit_cast(bf16x8, buf.e0);
    const bf16x8 b1 = __builtin_bit_cast(bf16x8, buf.e1);
    const bf16x8 b2 = __builtin_bit_cast(bf16x8, buf.e2);
    const bf16x8 b3 = __builtin_bit_cast(bf16x8, buf.e3);
    acc[0] = __builtin_amdgcn_mfma_f32_16x16x32_bf16(ah, b0, acc[0], 0, 0, 0);
    acc[0] = __builtin_amdgcn_mfma_f32_16x16x32_bf16(al, b0, acc[0], 0, 0, 0);
    acc[1] = __builtin_amdgcn_mfma_f32_16x16x32_bf16(ah, b1, acc[1], 0, 0, 0);
    acc[1] = __builtin_amdgcn_mfma_f32_16x16x32_bf16(al, b1, acc[1], 0, 0, 0);
    acc[2] = __builtin_amdgcn_mfma_f32_16x16x32_bf16(ah, b2, acc[2], 0, 0, 0);
    acc[2] = __builtin_amdgcn_mfma_f32_16x16x32_bf16(al, b2, acc[2], 0, 0, 0);
    acc[3] = __builtin_amdgcn_mfma_f32_16x16x32_bf16(ah, b3, acc[3], 0, 0, 0);
    acc[3] = __builtin_amdgcn_mfma_f32_16x16x32_bf16(al, b3, acc[3], 0, 0, 0);
  };

  PF pfA, pfB;                       // named ping-pong: static indexing
  loadpf(pfA, 0);
  for (int ks = 0; ks < KSTEPS; ks += 2) {
    loadpf(pfB, ks + 1);             // in flight during compute(pfA)
    compute(pfA);
    if (ks + 2 < KSTEPS) loadpf(pfA, ks + 2);
    compute(pfB);
  }

  // C/D layout (m89/R6-verified): col = lane&15, row = (lane>>4)*4 + reg
  #pragma unroll
  for (int qt = 0; qt < 4; ++qt)
    #pragma unroll
    for (int r = 0; r < 4; ++r)
      T_lds[wid * 16 + kg * 4 + r][qt * 16 + l15] = acc[qt][r];
  __syncthreads();

  // --- stage 2: S[p,q] += sum_{rows with p} T[row,q], via sorted runs ---
  {
    const int q = tid & 63, quarter = tid >> 6;   // wave == quarter
    float s = 0.0f;
    int pcur = -1;
    for (int k2 = 0; k2 < H_ROWS / 4; ++k2) {
      const int row = orderR[quarter * (H_ROWS / 4) + k2];  // wave-uniform
      const int p   = adds_s[row0 + row];                   // wave-uniform
      if (p != pcur) {                                      // uniform branch
        if (pcur >= 0 && q < NPOS) atomicAdd(&acc2[pcur * 52 + q], s);
        pcur = p; s = 0.0f;
      }
      s += T_lds[row][q];                                   // conflict-free
    }
    if (pcur >= 0 && q < NPOS) atomicAdd(&acc2[pcur * 52 + q], s);
  }
  __syncthreads();

  // --- flush: plain coalesced stores to this block's private slice ---
  float* __restrict__ gp = g_part + (size_t)blockIdx.x * PSTRIDE;
  for (int bin = tid; bin < NBINS; bin += H_THREADS)
    gp[bin] = acc2[(bin / NPOS) * 52 + (bin % NPOS)];
}

// ---------------------------------------------------------------------------
// Kernel 1.5: g_hist[bin] = sum over 2048 slices of g_part[slice][bin].
// ---------------------------------------------------------------------------
__global__ __launch_bounds__(R_THREADS) void reduce_kernel(
    const float* __restrict__ g_part, float* __restrict__ g_hist) {
  __shared__ float red[4][64];
  const int bx  = blockIdx.x % R_BINGRP;
  const int py  = blockIdx.x / R_BINGRP;
  const int w   = threadIdx.x >> 6, l = threadIdx.x & 63;
  const int bin = bx * 64 + l;

  float s = 0.0f;
  if (bin < NBINS) {
    const float* base = g_part + ((size_t)py * 128 + w * 32) * PSTRIDE + bin;
    #pragma unroll
    for (int r = 0; r < 32; ++r) s += base[(size_t)r * PSTRIDE];
  }
  red[w][l] = s;
  __syncthreads();
  if (w == 0 && bin < NBINS)
    atomicAdd(&g_hist[bin], red[0][l] + red[1][l] + red[2][l] + red[3][l]);
}

// ---------------------------------------------------------------------------
// Kernel 2: out = s_arc + ALPHA * sigmoid(g_hist)[pos-pair bin]
// Measured ~6.1 TB/s (HBM roofline) — unchanged.
// ---------------------------------------------------------------------------
__global__ __launch_bounds__(A_THREADS) void apply_kernel(
    const float* __restrict__ s, const int* __restrict__ pos,
    const float* __restrict__ g_hist, float* __restrict__ out) {
  __shared__ float sig[NBINS];
  __shared__ int   pos_s[SL];

  const int tid = threadIdx.x;
  const int b   = blockIdx.x / BLOCKS_PER_B;
  const int i0  = (blockIdx.x % BLOCKS_PER_B) * ROWS_PER_BLOCK;

  ((int4*)pos_s)[tid] = ((const int4*)(pos + (size_t)b * SL))[tid];
  for (int k = tid; k < NBINS; k += A_THREADS) {
    const float h = g_hist[k];
    sig[k] = 1.0f / (1.0f + __expf(-h));
  }
  __syncthreads();

  const int4 pj = ((const int4*)pos_s)[tid];
  const size_t rowoff = ((size_t)b * SL + i0) * SL;
  const float4* __restrict__ srow = (const float4*)(s + rowoff);
  float4* __restrict__ orow = (float4*)(out + rowoff);

  for (int r = 0; r < ROWS_PER_BLOCK; ++r) {
    const int base = pos_s[i0 + r] * NPOS;    // wave-uniform broadcast
    const float4 sv = srow[(size_t)r * (SL / 4) + tid];
    float4 ov;
    ov.x = sv.x + ALPHA * sig[base + pj.x];
    ov.y = sv.y + ALPHA * sig[base + pj.y];
    ov.z = sv.z + ALPHA * sig[base + pj.z];
    ov.w = sv.w + ALPHA * sig[base + pj.w];
    orow[(size_t)r * (SL / 4) + tid] = ov;
  }
}

extern "C" void kernel_launch(void* const* d_in, const int* in_sizes, int n_in,
                              void* d_out, int out_size, void* d_ws, size_t ws_size,
                              hipStream_t stream) {
  const float* a_arc = (const float*)d_in[0];
  const float* s_arc = (const float*)d_in[1];
  const int*   adds  = (const int*)d_in[2];
  const int*   pos   = (const int*)d_in[3];
  float* out    = (float*)d_out;
  float* g_hist = (float*)d_ws;                  // 2500 floats
  float* g_part = g_hist + 4096;                 // 2048 x 2560 floats = 21 MB
  uint4* efrag  = (uint4*)(g_part + (size_t)H_BLOCKS * PSTRIDE);  // 8 MB

  // g_hist is atomically accumulated by reduce_kernel -> zero it each call.
  // g_part/efrag need NO init: every slot is overwritten each call.
  hipMemsetAsync(g_hist, 0, NBINS * sizeof(float), stream);

  efrag_kernel <<<E_BLOCKS, E_THREADS, 0, stream>>>(adds, efrag);
  hist_mfma    <<<H_BLOCKS, H_THREADS, 0, stream>>>(a_arc, adds, efrag, g_part);
  reduce_kernel<<<R_BLOCKS, R_THREADS, 0, stream>>>(g_part, g_hist);
  apply_kernel <<<A_BLOCKS, A_THREADS, 0, stream>>>(s_arc, pos, g_hist, out);
}

// Round 11
// 180.527 us; speedup vs baseline: 1.1074x; 1.1074x over previous
//
#include <hip/hip_runtime.h>

// Problem constants (fixed by setup_inputs):
//   a_arc, s_arc : [64, 1024, 1024] f32
//   adds, pos    : [64, 1024] int32 in [0, 50)
constexpr int NPOS  = 50;
constexpr int NBINS = NPOS * NPOS;   // 2500
constexpr int SL    = 1024;
constexpr int BZ    = 64;
constexpr float ALPHA = 0.3f;

// ---------------- hist (row-gather) config ----------------
// Block = (batch b, p-range rg). Ranges: {7,7,6,6,6,6,6,6} cover p=0..49.
constexpr int NRNG      = 8;
constexpr int PSLICE    = 352;                 // per-block output slice (floats)
constexpr int H_THREADS = 256;                 // thread t owns cols 4t..4t+3
constexpr int H_BLOCKS  = BZ * NRNG;           // 512

__device__ __forceinline__ int rng_lo(int r) { return r < 2 ? 7 * r : 14 + 6 * (r - 2); }
__device__ __forceinline__ int rng_sz(int r) { return r < 2 ? 7 : 6; }

// ---------------- reduce2 / apply config ----------------
constexpr int R2_THREADS = 256;
constexpr int R2_BLOCKS  = (NBINS + R2_THREADS - 1) / R2_THREADS;  // 10
constexpr int A_THREADS      = 256;
constexpr int ROWS_PER_BLOCK = 32;
constexpr int BLOCKS_PER_B   = SL / ROWS_PER_BLOCK;   // 32
constexpr int A_BLOCKS       = BZ * BLOCKS_PER_B;     // 2048

// ---------------------------------------------------------------------------
// Kernel 1: per-(b, p-range) partials. Rows of the range are gathered via
// counting sort and streamed as FULL 4-KB contiguous rows (1 KB per
// wave-instruction) — every prior variant read A in 128-256 B pieces and
// pinned at ~2.7 TB/s; apply's 1-KB pattern gets 6.1 TB/s. Register
// accumulation across each p-run; ONE plain exclusive LDS store per p.
// ---------------------------------------------------------------------------
__global__ __launch_bounds__(H_THREADS) void hist_gather(
    const float* __restrict__ a, const int* __restrict__ adds,
    float* __restrict__ g_part) {
  __shared__ int   adds_s[SL];          // 4 KB
  __shared__ float accL[8][SL];         // 32 KB: [p_loc][col]; slot 7 = dummy
  __shared__ int   list[SL + 8];        // 4 KB: (p_loc<<12)|row, sorted by p
  __shared__ int   order2[SL];          // 4 KB: cols sorted by q
  __shared__ int   cnt8[8], off8[8];
  __shared__ int   cntQ[NPOS], offQs[NPOS], offQm[NPOS];
  __shared__ int   nrows_s;

  const int tid = threadIdx.x;
  const int b   = blockIdx.x / NRNG;
  const int rg  = blockIdx.x % NRNG;
  const int lo  = rng_lo(rg), sz = rng_sz(rg);

  ((int4*)adds_s)[tid] = ((const int4*)(adds + (size_t)b * SL))[tid];
  #pragma unroll
  for (int p = 0; p < 8; ++p) ((float4*)&accL[p][0])[tid] = float4{0, 0, 0, 0};
  if (tid < 8) cnt8[tid] = 0;
  if (tid < NPOS) cntQ[tid] = 0;
  __syncthreads();

  // --- counting sorts: range-rows by p_loc, all cols by q (verified) ---
  for (int i = tid; i < SL; i += H_THREADS) {
    const int p = adds_s[i];
    const int pl = p - lo;
    if ((unsigned)pl < (unsigned)sz) atomicAdd(&cnt8[pl], 1);
    atomicAdd(&cntQ[p], 1);
  }
  __syncthreads();
  if (tid == 0) {                       // wave 0: row prefix
    int run = 0;
    #pragma unroll
    for (int c = 0; c < 8; ++c) { off8[c] = run; run += cnt8[c]; }
    nrows_s = run;
  } else if (tid == 64) {               // wave 1: col prefix, concurrent
    int run = 0;
    for (int c = 0; c < NPOS; ++c) { offQs[c] = run; offQm[c] = run; run += cntQ[c]; }
  }
  __syncthreads();
  for (int i = tid; i < SL; i += H_THREADS) {
    const int p = adds_s[i];
    const int pl = p - lo;
    if ((unsigned)pl < (unsigned)sz)
      list[atomicAdd(&off8[pl], 1)] = (pl << 12) | i;
    order2[atomicAdd(&offQm[p], 1)] = i;
  }
  __syncthreads();
  const int N    = nrows_s;
  const int Npad = (N + 7) & ~7;
  if (tid < 8 && N + tid < Npad)        // pad: sentinel p_loc=7, valid row
    list[N + tid] = (7 << 12) | (N > 0 ? (list[N - 1] & 0xFFF) : 0);
  __syncthreads();

  // --- main loop: stream sorted rows, 8-deep ping-pong, 4-KB-granular ---
  const float4* __restrict__ Ab = (const float4*)(a + (size_t)b * SL * SL);
  float4 creg = {0, 0, 0, 0};
  int pcur = 7;

  int    eA[8], eB[8];
  float4 vA[8], vB[8];
  auto loadbank = [&](int (&e)[8], float4 (&v)[8], int k) {
    #pragma unroll
    for (int u = 0; u < 8; ++u) {
      e[u] = __builtin_amdgcn_readfirstlane(list[k + u]);  // uniform -> SGPR
      v[u] = Ab[(size_t)(e[u] & 0xFFF) * (SL / 4) + tid];  // 1 KB/wave-instr
    }
  };
  auto procbank = [&](int (&e)[8], float4 (&v)[8]) {
    #pragma unroll
    for (int u = 0; u < 8; ++u) {
      const int pl = e[u] >> 12;
      if (pl != pcur) {                 // block-uniform scalar branch
        ((float4*)&accL[pcur][0])[tid] = creg;   // one store per p-run
        creg = float4{0, 0, 0, 0};
        pcur = pl;
      }
      creg.x += v[u].x; creg.y += v[u].y; creg.z += v[u].z; creg.w += v[u].w;
    }
  };

  if (Npad > 0) {
    pcur = list[0] >> 12;
    loadbank(eA, vA, 0);
    for (int k = 0; k < Npad; k += 16) {
      if (k + 8 < Npad) loadbank(eB, vB, k + 8);
      procbank(eA, vA);
      if (k + 16 < Npad) loadbank(eA, vA, k + 16);
      if (k + 8 < Npad) procbank(eB, vB);
    }
    ((float4*)&accL[pcur][0])[tid] = creg;       // final flush (7 = dummy ok)
  }
  __syncthreads();

  // --- col reduce: slice[pl*50+q] = sum_{cols j: adds[j]==q} accL[pl][j] ---
  float* __restrict__ gp = g_part + (size_t)blockIdx.x * PSLICE;
  for (int bin = tid; bin < sz * NPOS; bin += H_THREADS) {
    const int pl = bin / NPOS, q = bin % NPOS;
    const int s0 = offQs[q], n = cntQ[q];
    float s = 0.0f;
    for (int k2 = 0; k2 < n; ++k2) s += accL[pl][order2[s0 + k2]];
    gp[bin] = s;                        // plain store, private slice
  }
}

// ---------------------------------------------------------------------------
// Kernel 1.5: g_hist[bin] = sum over 64 batches of that bin's range-slice.
// Plain stores; each bin owned by one thread -> no atomics, no memset.
// ---------------------------------------------------------------------------
__global__ __launch_bounds__(R2_THREADS) void reduce2(
    const float* __restrict__ g_part, float* __restrict__ g_hist) {
  const int bin = blockIdx.x * R2_THREADS + threadIdx.x;
  if (bin >= NBINS) return;
  const int p = bin / NPOS, q = bin % NPOS;
  const int rg = (p < 14) ? p / 7 : 2 + (p - 14) / 6;
  const int pl = (p < 14) ? p % 7 : (p - 14) % 6;
  float s = 0.0f;
  #pragma unroll 8
  for (int bb = 0; bb < BZ; ++bb)
    s += g_part[(size_t)(bb * NRNG + rg) * PSLICE + pl * NPOS + q];
  g_hist[bin] = s;
}

// ---------------------------------------------------------------------------
// Kernel 2: out = s_arc + ALPHA * sigmoid(g_hist)[pos-pair bin]
// Measured ~6.1 TB/s (HBM roofline) — unchanged.
// ---------------------------------------------------------------------------
__global__ __launch_bounds__(A_THREADS) void apply_kernel(
    const float* __restrict__ s, const int* __restrict__ pos,
    const float* __restrict__ g_hist, float* __restrict__ out) {
  __shared__ float sig[NBINS];
  __shared__ int   pos_s[SL];

  const int tid = threadIdx.x;
  const int b   = blockIdx.x / BLOCKS_PER_B;
  const int i0  = (blockIdx.x % BLOCKS_PER_B) * ROWS_PER_BLOCK;

  ((int4*)pos_s)[tid] = ((const int4*)(pos + (size_t)b * SL))[tid];
  for (int k = tid; k < NBINS; k += A_THREADS) {
    const float h = g_hist[k];
    sig[k] = 1.0f / (1.0f + __expf(-h));
  }
  __syncthreads();

  const int4 pj = ((const int4*)pos_s)[tid];
  const size_t rowoff = ((size_t)b * SL + i0) * SL;
  const float4* __restrict__ srow = (const float4*)(s + rowoff);
  float4* __restrict__ orow = (float4*)(out + rowoff);

  for (int r = 0; r < ROWS_PER_BLOCK; ++r) {
    const int base = pos_s[i0 + r] * NPOS;    // wave-uniform broadcast
    const float4 sv = srow[(size_t)r * (SL / 4) + tid];
    float4 ov;
    ov.x = sv.x + ALPHA * sig[base + pj.x];
    ov.y = sv.y + ALPHA * sig[base + pj.y];
    ov.z = sv.z + ALPHA * sig[base + pj.z];
    ov.w = sv.w + ALPHA * sig[base + pj.w];
    orow[(size_t)r * (SL / 4) + tid] = ov;
  }
}

extern "C" void kernel_launch(void* const* d_in, const int* in_sizes, int n_in,
                              void* d_out, int out_size, void* d_ws, size_t ws_size,
                              hipStream_t stream) {
  const float* a_arc = (const float*)d_in[0];
  const float* s_arc = (const float*)d_in[1];
  const int*   adds  = (const int*)d_in[2];
  const int*   pos   = (const int*)d_in[3];
  float* out    = (float*)d_out;
  float* g_hist = (float*)d_ws;                 // 2500 floats
  float* g_part = g_hist + 4096;                // 512 x 352 floats = 0.72 MB

  // No memset needed: g_part slices and g_hist are fully overwritten with
  // plain stores every call (no atomic accumulation anywhere).
  hist_gather <<<H_BLOCKS, H_THREADS, 0, stream>>>(a_arc, adds, g_part);
  reduce2     <<<R2_BLOCKS, R2_THREADS, 0, stream>>>(g_part, g_hist);
  apply_kernel<<<A_BLOCKS, A_THREADS, 0, stream>>>(s_arc, pos, g_hist, out);
}